// Round 5
// baseline (367.702 us; speedup 1.0000x reference)
//
#include <hip/hip_runtime.h>

#define NN 50000
#define EE 800000
#define EP (EE + NN)   // 850000 edges incl. self loops
#define NH 4
#define HC 256
#define NOUT 256
#define NEG_SLOPE 0.2f
#define LN_EPS 1e-5f
#define NB 49          // ceil(NN/1024)

typedef unsigned short u16;
typedef __attribute__((ext_vector_type(8))) short bf16x8;
typedef __attribute__((ext_vector_type(8))) unsigned short ushort8;
typedef __attribute__((ext_vector_type(4))) float f32x4;

__device__ __forceinline__ u16 f2bf(float f) {
    unsigned int u = __float_as_uint(f);
    u += 0x7fff + ((u >> 16) & 1);           // round-to-nearest-even
    return (u16)(u >> 16);
}
__device__ __forceinline__ float bf2f(u16 s) {
    return __uint_as_float(((unsigned int)s) << 16);
}

// ---------------- edge index handling (int32 vs int64 hedge) ----------------
__global__ void k_detect(const int* __restrict__ raw, int* __restrict__ flag) {
    __shared__ int any;
    if (threadIdx.x == 0) any = 0;
    __syncthreads();
    int found = 0;
    for (int i = threadIdx.x; i < 4096; i += 256)
        if (raw[2 * i + 1] != 0) found = 1;
    if (found) atomicOr(&any, 1);
    __syncthreads();
    if (threadIdx.x == 0) *flag = any;   // 1 => int32 layout, 0 => int64 (low words)
}

// degree histogram over real edges only (self loops folded in as deg+1)
__global__ void k_hist(const int* __restrict__ raw, const int* __restrict__ flag,
                       int* __restrict__ deg) {
    int e = blockIdx.x * blockDim.x + threadIdx.x;
    if (e >= EE) return;
    int d = (*flag) ? raw[EE + e] : raw[2 * (EE + e)];
    atomicAdd(&deg[d], 1);
}

// ---------------- 3-phase scan: (deg+1) -> rowptr/cursor ----------------
__global__ void k_scanA(const int* __restrict__ deg, int* __restrict__ tmp,
                        int* __restrict__ bsum) {
    __shared__ int ws[16];
    int lane = threadIdx.x & 63, wid = threadIdx.x >> 6;
    int i = blockIdx.x * 1024 + threadIdx.x;
    int x = (i < NN) ? deg[i] + 1 : 0;
    #pragma unroll
    for (int o = 1; o < 64; o <<= 1) {
        int t = __shfl_up(x, o, 64);
        if (lane >= o) x += t;
    }
    if (lane == 63) ws[wid] = x;
    __syncthreads();
    if (wid == 0 && lane < 16) {
        int s = ws[lane];
        #pragma unroll
        for (int o = 1; o < 16; o <<= 1) {
            int t = __shfl_up(s, o, 64);
            if (lane >= o) s += t;
        }
        ws[lane] = s;
    }
    __syncthreads();
    x += (wid > 0) ? ws[wid - 1] : 0;
    if (i < NN) tmp[i] = x;
    if (threadIdx.x == 1023) bsum[blockIdx.x] = x;
}

__global__ void k_scanB(int* __restrict__ bsum, int nb) {
    int lane = threadIdx.x & 63;
    int orig = (lane < nb) ? bsum[lane] : 0;
    int x = orig;
    #pragma unroll
    for (int o = 1; o < 64; o <<= 1) {
        int t = __shfl_up(x, o, 64);
        if (lane >= o) x += t;
    }
    if (lane < nb) bsum[lane] = x - orig;   // exclusive
}

__global__ void k_scanC(const int* __restrict__ tmp, const int* __restrict__ bsum,
                        const int* __restrict__ deg, int* __restrict__ rowptr,
                        int* __restrict__ cursor) {
    int i = blockIdx.x * 1024 + threadIdx.x;
    if (i >= NN) return;
    int fin = tmp[i] + bsum[blockIdx.x];
    rowptr[i + 1] = fin;
    cursor[i] = fin - (deg[i] + 1);
    if (i == 0) rowptr[0] = 0;
}

// scatter reading raw edges directly (incl. analytic self loops)
__global__ void k_scatter(const int* __restrict__ raw, const int* __restrict__ flag,
                          int* __restrict__ cursor, int* __restrict__ esrc) {
    int e = blockIdx.x * blockDim.x + threadIdx.x;
    if (e >= EP) return;
    int s, d;
    if (e >= EE) { s = e - EE; d = s; }
    else if (*flag) { s = raw[e];     d = raw[EE + e]; }
    else            { s = raw[2 * e]; d = raw[2 * (EE + e)]; }
    int pos = atomicAdd(&cursor[d], 1);
    esrc[pos] = s;
}

// ---------------- weight cast: w[K][N] fp32 -> wT[N][K] bf16 ----------------
__global__ void k_cast_wT(const float* __restrict__ w, u16* __restrict__ wT, int K, int N) {
    int i = blockIdx.x * blockDim.x + threadIdx.x;
    if (i >= K * N) return;
    int k = i / N, j = i - k * N;
    wT[j * K + k] = f2bf(w[i]);
}

// ------- input projection (MFMA, fused fp32->bf16 cast of x) -------
// x [NN][128] fp32, wT [64][128] bf16 -> h0 [NN][64] bf16
__global__ void k_proj_mfma(const float* __restrict__ x, const u16* __restrict__ wT,
                            const float* __restrict__ bias, u16* __restrict__ h0) {
    int wave = threadIdx.x >> 6, lane = threadIdx.x & 63;
    int lr = lane & 15, lk = lane >> 4;
    int rowbase = (blockIdx.x * 4 + wave) * 64;
    f32x4 acc[4][4];
    #pragma unroll
    for (int mf = 0; mf < 4; ++mf)
        #pragma unroll
        for (int nf = 0; nf < 4; ++nf) acc[mf][nf] = (f32x4)0.f;
    for (int kk = 0; kk < 128; kk += 32) {
        bf16x8 a[4], b[4];
        #pragma unroll
        for (int mf = 0; mf < 4; ++mf) {
            int row = rowbase + mf * 16 + lr;
            if (row < NN) {
                float4 v0 = *(const float4*)&x[(size_t)row * 128 + kk + lk * 8];
                float4 v1 = *(const float4*)&x[(size_t)row * 128 + kk + lk * 8 + 4];
                a[mf][0] = (short)f2bf(v0.x); a[mf][1] = (short)f2bf(v0.y);
                a[mf][2] = (short)f2bf(v0.z); a[mf][3] = (short)f2bf(v0.w);
                a[mf][4] = (short)f2bf(v1.x); a[mf][5] = (short)f2bf(v1.y);
                a[mf][6] = (short)f2bf(v1.z); a[mf][7] = (short)f2bf(v1.w);
            } else a[mf] = (bf16x8)(short)0;
        }
        #pragma unroll
        for (int nf = 0; nf < 4; ++nf)
            b[nf] = *(const bf16x8*)&wT[(size_t)(nf * 16 + lr) * 128 + kk + lk * 8];
        #pragma unroll
        for (int mf = 0; mf < 4; ++mf)
            #pragma unroll
            for (int nf = 0; nf < 4; ++nf)
                acc[mf][nf] = __builtin_amdgcn_mfma_f32_16x16x32_bf16(a[mf], b[nf], acc[mf][nf], 0, 0, 0);
    }
    #pragma unroll
    for (int mf = 0; mf < 4; ++mf)
        #pragma unroll
        for (int r = 0; r < 4; ++r) {
            int row = rowbase + mf * 16 + lk * 4 + r;
            if (row < NN) {
                #pragma unroll
                for (int nf = 0; nf < 4; ++nf) {
                    int col = nf * 16 + lr;
                    h0[(size_t)row * 64 + col] = f2bf(fmaxf(acc[mf][nf][r] + bias[col], 0.f));
                }
            }
        }
}

// ------- GAT linear (MFMA) + fused attention dots -------
template<int K>
__global__ void k_lin_att_mfma(const u16* __restrict__ h, const u16* __restrict__ wT,
                               const float* __restrict__ att_s, const float* __restrict__ att_d,
                               u16* __restrict__ hp, float* __restrict__ as_, float* __restrict__ ad_) {
    int wave = threadIdx.x >> 6, lane = threadIdx.x & 63;
    int lr = lane & 15, lk = lane >> 4;
    int rowbase = blockIdx.x * 64;
    f32x4 acc[4][4];
    #pragma unroll
    for (int mf = 0; mf < 4; ++mf)
        #pragma unroll
        for (int nf = 0; nf < 4; ++nf) acc[mf][nf] = (f32x4)0.f;
    for (int kk = 0; kk < K; kk += 32) {
        bf16x8 a[4], b[4];
        #pragma unroll
        for (int mf = 0; mf < 4; ++mf) {
            int row = rowbase + mf * 16 + lr;
            a[mf] = (row < NN) ? *(const bf16x8*)&h[(size_t)row * K + kk + lk * 8]
                               : (bf16x8)(short)0;
        }
        #pragma unroll
        for (int nf = 0; nf < 4; ++nf)
            b[nf] = *(const bf16x8*)&wT[(size_t)(wave * 64 + nf * 16 + lr) * K + kk + lk * 8];
        #pragma unroll
        for (int mf = 0; mf < 4; ++mf)
            #pragma unroll
            for (int nf = 0; nf < 4; ++nf)
                acc[mf][nf] = __builtin_amdgcn_mfma_f32_16x16x32_bf16(a[mf], b[nf], acc[mf][nf], 0, 0, 0);
    }
    float asv[4], adv[4];
    #pragma unroll
    for (int nf = 0; nf < 4; ++nf) {
        int col = wave * 64 + nf * 16 + lr;
        asv[nf] = att_s[col];
        adv[nf] = att_d[col];
    }
    #pragma unroll
    for (int mf = 0; mf < 4; ++mf) {
        float ps[4] = {0.f, 0.f, 0.f, 0.f}, pd[4] = {0.f, 0.f, 0.f, 0.f};
        #pragma unroll
        for (int r = 0; r < 4; ++r) {
            int row = rowbase + mf * 16 + lk * 4 + r;
            #pragma unroll
            for (int nf = 0; nf < 4; ++nf) {
                float v = acc[mf][nf][r];
                ps[r] += v * asv[nf];
                pd[r] += v * adv[nf];
                if (row < NN)
                    hp[(size_t)row * HC + wave * 64 + nf * 16 + lr] = f2bf(v);
            }
        }
        #pragma unroll
        for (int r = 0; r < 4; ++r) {
            float s = ps[r], d = pd[r];
            #pragma unroll
            for (int o = 1; o < 16; o <<= 1) {
                s += __shfl_xor(s, o, 16);
                d += __shfl_xor(d, o, 16);
            }
            int row = rowbase + mf * 16 + lk * 4 + r;
            if (lr == 0 && row < NN) {
                as_[row * NH + wave] = s;
                ad_[row * NH + wave] = d;
            }
        }
    }
}

// ---- single-pass fused agg + softmax-norm + bias/LN/ReLU ----
// wave per node; per 64-edge chunk: lanes compute w (LDS-staged), then
// quarter-wave-per-edge (16 lanes x 32B) gather with 1-ahead prefetch.
#define CHUNK 64
__global__ void k_agg_ln(const int* __restrict__ rowptr, const int* __restrict__ esrc,
                         const u16* __restrict__ hp, const float* __restrict__ as_,
                         const float* __restrict__ ad_,
                         const float* __restrict__ bias, const float* __restrict__ g,
                         const float* __restrict__ b, u16* __restrict__ outv) {
    __shared__ float sw[4][CHUNK][4];
    __shared__ int   ss[4][CHUNK];
    int wave = threadIdx.x >> 6, lane = threadIdx.x & 63;
    int n = blockIdx.x * 4 + wave;
    int start = rowptr[n], end = rowptr[n + 1];
    float4 adv = *(const float4*)&ad_[n * NH];
    int p = lane & 15, grp = lane >> 4;
    int c = p * 16, hd = p >> 2;
    float acc[16];
    #pragma unroll
    for (int k = 0; k < 16; ++k) acc[k] = 0.f;
    float z0 = 0.f, z1 = 0.f, z2 = 0.f, z3 = 0.f;

    for (int base = start; base < end; base += CHUNK) {
        int m = end - base; if (m > CHUNK) m = CHUNK;
        // phase 1: lane-parallel edge weights into LDS
        if (lane < m) {
            int s = esrc[base + lane];
            float4 asv = *(const float4*)&as_[s * NH];
            float e0 = asv.x + adv.x; e0 = e0 > 0.f ? e0 : e0 * NEG_SLOPE; float w0 = __expf(e0);
            float e1 = asv.y + adv.y; e1 = e1 > 0.f ? e1 : e1 * NEG_SLOPE; float w1 = __expf(e1);
            float e2 = asv.z + adv.z; e2 = e2 > 0.f ? e2 : e2 * NEG_SLOPE; float w2 = __expf(e2);
            float e3 = asv.w + adv.w; e3 = e3 > 0.f ? e3 : e3 * NEG_SLOPE; float w3 = __expf(e3);
            ss[wave][lane] = s;
            *(float4*)&sw[wave][lane][0] = make_float4(w0, w1, w2, w3);
            z0 += w0; z1 += w1; z2 += w2; z3 += w3;
        }
        // phase 2: 4 edges per wave-iteration, 1-ahead prefetch (wave-sync LDS)
        int e = grp;
        bool v = e < m;
        int s = v ? ss[wave][e] : 0;
        float w = v ? sw[wave][e][hd] : 0.f;
        ushort8 lo = *(const ushort8*)&hp[(size_t)s * HC + c];
        ushort8 hi = *(const ushort8*)&hp[(size_t)s * HC + c + 8];
        int nIter = (m + 3) >> 2;
        for (int it = 0; it < nIter; ++it) {
            int en = e + 4;
            bool vn = en < m;
            int sn = vn ? ss[wave][en] : 0;
            float wn = vn ? sw[wave][en][hd] : 0.f;
            ushort8 lon = *(const ushort8*)&hp[(size_t)sn * HC + c];
            ushort8 hin = *(const ushort8*)&hp[(size_t)sn * HC + c + 8];
            #pragma unroll
            for (int k = 0; k < 8; ++k) acc[k]     += w * bf2f(lo[k]);
            #pragma unroll
            for (int k = 0; k < 8; ++k) acc[k + 8] += w * bf2f(hi[k]);
            e = en; w = wn; lo = lon; hi = hin;
        }
    }
    // combine the 4 edge-groups (channels identical across groups)
    #pragma unroll
    for (int k = 0; k < 16; ++k) {
        acc[k] += __shfl_xor(acc[k], 16, 64);
        acc[k] += __shfl_xor(acc[k], 32, 64);
    }
    // softmax denominators
    #pragma unroll
    for (int o = 32; o >= 1; o >>= 1) {
        z0 += __shfl_xor(z0, o, 64);
        z1 += __shfl_xor(z1, o, 64);
        z2 += __shfl_xor(z2, o, 64);
        z3 += __shfl_xor(z3, o, 64);
    }
    float zh = hd == 0 ? z0 : hd == 1 ? z1 : hd == 2 ? z2 : z3;
    float iz = 1.f / (zh + 1e-16f);
    // bias + LN + relu on 16 channels per lane (lanes 0..15 == full row)
    float xv[16], sum = 0.f;
    #pragma unroll
    for (int k = 0; k < 16; ++k) { xv[k] = acc[k] * iz + bias[c + k]; sum += xv[k]; }
    #pragma unroll
    for (int o = 8; o >= 1; o >>= 1) sum += __shfl_xor(sum, o, 64);
    float mu = sum * (1.f / HC);
    float vs = 0.f;
    #pragma unroll
    for (int k = 0; k < 16; ++k) { float d = xv[k] - mu; vs += d * d; }
    #pragma unroll
    for (int o = 8; o >= 1; o >>= 1) vs += __shfl_xor(vs, o, 64);
    float rs = rsqrtf(vs * (1.f / HC) + LN_EPS);
    if (grp == 0) {
        ushort8 y0, y1;
        #pragma unroll
        for (int k = 0; k < 8; ++k) {
            y0[k] = f2bf(fmaxf((xv[k] - mu) * rs * g[c + k] + b[c + k], 0.f));
            y1[k] = f2bf(fmaxf((xv[k + 8] - mu) * rs * g[c + k + 8] + b[c + k + 8], 0.f));
        }
        *(ushort8*)&outv[(size_t)n * HC + c]     = y0;
        *(ushort8*)&outv[(size_t)n * HC + c + 8] = y1;
    }
}

// ---------------- mean pool (column sums, bf16 in) ----------------
__global__ void k_colsum(const u16* __restrict__ v, float* __restrict__ gacc) {
    int j = threadIdx.x;
    float s = 0.f;
    for (int n = blockIdx.x; n < NN; n += gridDim.x)
        s += bf2f(v[(size_t)n * HC + j]);
    atomicAdd(&gacc[j], s);
}

// ---------------- final GEMV: out = (g/N) @ w_out + b_out ----------------
__global__ void k_final(const float* __restrict__ gacc, const float* __restrict__ w,
                        const float* __restrict__ b, float* __restrict__ out) {
    int o = threadIdx.x;
    float acc = b[o];
    for (int k = 0; k < HC; ++k)
        acc += (gacc[k] * (1.f / NN)) * w[k * NOUT + o];
    out[o] = acc;
}

extern "C" void kernel_launch(void* const* d_in, const int* in_sizes, int n_in,
                              void* d_out, int out_size, void* d_ws, size_t ws_size,
                              hipStream_t stream) {
    const float* x      = (const float*)d_in[0];
    const int*   eiraw  = (const int*)d_in[1];
    const float* w_in   = (const float*)d_in[2];
    const float* b_in   = (const float*)d_in[3];
    const float* lin0_w = (const float*)d_in[4];
    const float* atts0  = (const float*)d_in[5];
    const float* attd0  = (const float*)d_in[6];
    const float* bias0  = (const float*)d_in[7];
    const float* ln0g   = (const float*)d_in[8];
    const float* ln0b   = (const float*)d_in[9];
    const float* lin1_w = (const float*)d_in[10];
    const float* atts1  = (const float*)d_in[11];
    const float* attd1  = (const float*)d_in[12];
    const float* bias1  = (const float*)d_in[13];
    const float* ln1g   = (const float*)d_in[14];
    const float* ln1b   = (const float*)d_in[15];
    const float* w_out  = (const float*)d_in[16];
    const float* b_out  = (const float*)d_in[17];
    float* out = (float*)d_out;

    char* ws = (char*)d_ws;
    size_t off = 0;
    auto alloc = [&](size_t bytes) {
        void* p = ws + off;
        off = (off + bytes + 255) & ~(size_t)255;
        return p;
    };
    int*   esrc   = (int*)  alloc((size_t)EP * 4);
    int*   deg    = (int*)  alloc((size_t)NN * 4);
    int*   cursor = (int*)  alloc((size_t)NN * 4);
    int*   tmp    = (int*)  alloc((size_t)NN * 4);
    int*   bsum   = (int*)  alloc(64 * 4);
    int*   rowptr = (int*)  alloc((size_t)(NN + 1) * 4);
    int*   flag   = (int*)  alloc(256);
    u16*   winT   = (u16*)  alloc((size_t)64 * 128 * 2);
    u16*   w0T    = (u16*)  alloc((size_t)256 * 64 * 2);
    u16*   w1T    = (u16*)  alloc((size_t)256 * 256 * 2);
    u16*   h0b    = (u16*)  alloc((size_t)NN * 64 * 2);
    u16*   hpb    = (u16*)  alloc((size_t)NN * HC * 2);
    u16*   h1b    = (u16*)  alloc((size_t)NN * HC * 2);
    float* as_    = (float*)alloc((size_t)NN * NH * 4);
    float* ad_    = (float*)alloc((size_t)NN * NH * 4);
    float* gacc   = (float*)alloc(HC * 4);

    // ---- edge prep + CSR (shared by both layers) ----
    hipMemsetAsync(deg, 0, (size_t)NN * 4, stream);
    k_detect<<<1, 256, 0, stream>>>(eiraw, flag);
    k_hist<<<(EE + 255) / 256, 256, 0, stream>>>(eiraw, flag, deg);
    k_scanA<<<NB, 1024, 0, stream>>>(deg, tmp, bsum);
    k_scanB<<<1, 64, 0, stream>>>(bsum, NB);
    k_scanC<<<NB, 1024, 0, stream>>>(tmp, bsum, deg, rowptr, cursor);
    k_scatter<<<(EP + 255) / 256, 256, 0, stream>>>(eiraw, flag, cursor, esrc);

    // ---- weight casts ----
    k_cast_wT<<<(128 * 64 + 255) / 256, 256, 0, stream>>>(w_in, winT, 128, 64);
    k_cast_wT<<<(64 * 256 + 255) / 256, 256, 0, stream>>>(lin0_w, w0T, 64, 256);
    k_cast_wT<<<(256 * 256 + 255) / 256, 256, 0, stream>>>(lin1_w, w1T, 256, 256);

    // ---- input projection (fused cast) ----
    k_proj_mfma<<<(NN + 255) / 256, 256, 0, stream>>>(x, winT, b_in, h0b);

    // ---- GAT layer 0 ----
    k_lin_att_mfma<64><<<(NN + 63) / 64, 256, 0, stream>>>(h0b, w0T, atts0, attd0, hpb, as_, ad_);
    k_agg_ln<<<NN / 4, 256, 0, stream>>>(rowptr, esrc, hpb, as_, ad_, bias0, ln0g, ln0b, h1b);

    // ---- GAT layer 1 ----
    k_lin_att_mfma<256><<<(NN + 63) / 64, 256, 0, stream>>>(h1b, w1T, atts1, attd1, hpb, as_, ad_);
    k_agg_ln<<<NN / 4, 256, 0, stream>>>(rowptr, esrc, hpb, as_, ad_, bias1, ln1g, ln1b, h1b);

    // ---- pool + output ----
    hipMemsetAsync(gacc, 0, HC * 4, stream);
    k_colsum<<<512, 256, 0, stream>>>(h1b, gacc);
    k_final<<<1, 256, 0, stream>>>(gacc, w_out, b_out, out);
}